// Round 9
// baseline (89.955 us; speedup 1.0000x reference)
//
#include <hip/hip_runtime.h>
#include <math.h>

#define NCL  27
#define CCH  512
#define HWPX 9216            // 96*96
#define NB   16
#define NPIX (NB * HWPX)     // 147456
#define EPSN 1e-12f
#define NCHK 32              // K chunks of 16

typedef short        short8 __attribute__((ext_vector_type(8)));
typedef unsigned int uint4v __attribute__((ext_vector_type(4)));
typedef float        f32x16 __attribute__((ext_vector_type(16)));

// RNE bf16 conversion for the (one-time) cluster prep
__device__ __forceinline__ unsigned short f2bf(float f) {
    unsigned u = __float_as_uint(f);
    return (unsigned short)((u + 0x7fffu + ((u >> 16) & 1u)) >> 16);
}
__device__ __forceinline__ float bf2f(unsigned short h) {
    return __uint_as_float(((unsigned)h) << 16);
}

// ---------------------------------------------------------------------------
// k0: normalize clusters (fp32), split into bf16 hi/lo (RNE), write
// A-fragments in 32x32x16 MFMA lane layout:
//   A[row=m][k] -> clA[chunk][lane][j], lane = m + 32*half, k = chunk*16+8*half+j
// rows 27..31 zero-pad. Also zero the 32 loss slots. grid = 32 x 64.
// ---------------------------------------------------------------------------
__global__ __launch_bounds__(64) void k0_prep(const float* __restrict__ cl,
                                              unsigned short* __restrict__ clAhi,
                                              unsigned short* __restrict__ clAlo,
                                              float* __restrict__ loss_acc) {
    const int n = blockIdx.x;            // A row 0..31
    const int t = threadIdx.x;
    float inv = 0.f;
    if (n < NCL) {
        const float* row = cl + n * CCH;
        float ss = 0.f;
#pragma unroll
        for (int i = 0; i < CCH / 64; ++i) {
            float v = row[i * 64 + t];
            ss = fmaf(v, v, ss);
        }
#pragma unroll
        for (int off = 32; off > 0; off >>= 1)
            ss += __shfl_xor(ss, off, 64);
        inv = 1.0f / fmaxf(sqrtf(ss), EPSN);
    }
    const int chunk = t >> 1;
    const int half  = t & 1;
    const int lane  = n + 32 * half;
    const size_t base = ((size_t)chunk * 64 + lane) * 8;
#pragma unroll
    for (int j = 0; j < 8; ++j) {
        const int k = chunk * 16 + 8 * half + j;
        float v = (n < NCL) ? cl[n * CCH + k] * inv : 0.f;
        unsigned short h = f2bf(v);
        float lo = v - bf2f(h);
        clAhi[base + j] = h;
        clAlo[base + j] = f2bf(lo);
    }
    if (n == 0 && t < 32) loss_acc[t * 32] = 0.f;   // 32 line-padded slots
}

// ---------------------------------------------------------------------------
// k1: streaming MFMA kernel. NO LDS, NO barriers, 1-wave blocks (grid 4608).
//  Wave = 32-pixel tile x 512 channels. Per K=16 chunk: 8 coalesced x loads
//  (fp32, read-once), 2 dwordx4 A-fragment loads (L2-resident), truncation
//  hi/lo split, v_perm packing, 3 MFMAs (ah*bh + al*bh + ah*bl ~= fp32).
//  unroll 4 -> ~40 loads in flight; launch_bounds(64,4) pins VGPR<=128 so
//  occupancy stays 4 waves/SIMD (grid avg 4.5).
//  C: col=lane&31=pixel, row=(r&3)+8*(r>>2)+4*half; valid rows < 27 only
//  (r<12 always, r=12..14 on half 0; r==15/half0 is pad row 27).
// ---------------------------------------------------------------------------
__global__ __launch_bounds__(64, 4) void k1_main(const float* __restrict__ x,
                                                 const unsigned short* __restrict__ clAhi,
                                                 const unsigned short* __restrict__ clAlo,
                                                 const float* __restrict__ alpha_p,
                                                 float* __restrict__ out,
                                                 float* __restrict__ loss_acc) {
    const int l    = threadIdx.x;
    const int px0  = blockIdx.x * 32;
    const int b    = px0 / HWPX;                  // uniform (32 | 9216)
    const int hw0  = px0 - b * HWPX;
    const int col  = l & 31;                      // pixel within tile
    const int half = l >> 5;                      // k-half

    const float* xg = x + ((size_t)b * CCH + 8 * half) * HWPX + hw0 + col;
    const unsigned short* pAh = clAhi + (size_t)l * 8;
    const unsigned short* pAl = clAlo + (size_t)l * 8;

    f32x16 acc = {0.f, 0.f, 0.f, 0.f, 0.f, 0.f, 0.f, 0.f,
                  0.f, 0.f, 0.f, 0.f, 0.f, 0.f, 0.f, 0.f};
    float ss = 0.f;

#pragma unroll 4
    for (int t = 0; t < NCHK; ++t) {
        float xv[8];
#pragma unroll
        for (int j = 0; j < 8; ++j)
            xv[j] = xg[(size_t)(t * 16 + j) * HWPX];   // coalesced 128B/half-wave

        short8 ah = *(const short8*)(pAh + (size_t)t * 512);   // dwordx4, L2-hit
        short8 al = *(const short8*)(pAl + (size_t)t * 512);

        unsigned ub[8], lb[8];
#pragma unroll
        for (int j = 0; j < 8; ++j) {
            ss = fmaf(xv[j], xv[j], ss);               // exact fp32 self-norm
            ub[j] = __float_as_uint(xv[j]);
            // exact low part vs truncated-bf16 hi: lo = v - trunc16(v)
            lb[j] = __float_as_uint(xv[j] - __uint_as_float(ub[j] & 0xFFFF0000u));
        }
        uint4v bhp, blp;
#pragma unroll
        for (int i = 0; i < 4; ++i) {
            // {hi16(odd) : hi16(even)} in one v_perm_b32
            bhp[i] = __builtin_amdgcn_perm(ub[2 * i + 1], ub[2 * i], 0x07060302u);
            blp[i] = __builtin_amdgcn_perm(lb[2 * i + 1], lb[2 * i], 0x07060302u);
        }
        short8 bh = __builtin_bit_cast(short8, bhp);
        short8 bl = __builtin_bit_cast(short8, blp);

        acc = __builtin_amdgcn_mfma_f32_32x32x16_bf16(ah, bh, acc, 0, 0, 0);
        acc = __builtin_amdgcn_mfma_f32_32x32x16_bf16(al, bh, acc, 0, 0, 0);
        acc = __builtin_amdgcn_mfma_f32_32x32x16_bf16(ah, bl, acc, 0, 0, 0);
    }

    // ---- epilogue ----
    ss += __shfl_xor(ss, 32, 64);                 // combine k-halves of pixel
    const float inv_x = 1.0f / fmaxf(sqrtf(ss), EPSN);
    const float alpha = alpha_p[0];

    float ip[16], ex[16];
#pragma unroll
    for (int r = 0; r < 16; ++r) {
        ip[r] = acc[r] * inv_x;                   // cosine (cl-norm folded in A)
        ex[r] = ip[r] * alpha;
    }

    // valid (row<27): r<12 always; r in 12..14 only on half 0
    float m = -1e30f;
#pragma unroll
    for (int r = 0; r < 12; ++r) m = fmaxf(m, ex[r]);
    if (half == 0) {
#pragma unroll
        for (int r = 12; r < 15; ++r) m = fmaxf(m, ex[r]);
    }
    m = fmaxf(m, __shfl_xor(m, 32, 64));          // max over all 27

    float sum = 0.f;
#pragma unroll
    for (int r = 0; r < 12; ++r) {
        ex[r] = __expf(ex[r] - m);
        sum += ex[r];
    }
#pragma unroll
    for (int r = 12; r < 16; ++r) {
        float e = (half == 0 && r < 15) ? __expf(ex[r] - m) : 0.f;
        ex[r] = e;
        sum += e;
    }
    sum += __shfl_xor(sum, 32, 64);               // denom over all 27
    const float inv_sum = 1.0f / sum;

    float lterm = 0.f;
    float* ob = out + 1 + (size_t)b * (NCL * HWPX) + hw0 + col;
#pragma unroll
    for (int r = 0; r < 16; ++r) {
        const int row = (r & 3) + 8 * (r >> 2) + 4 * half;
        if (r < 12 || (half == 0 && r < 15)) {    // row < 27 only
            float pr = ex[r] * inv_sum;
            ob[(size_t)row * HWPX] = pr;          // coalesced 128B segments
            lterm = fmaf(pr, ip[r], lterm);
        }
    }

    // per-(pixel,half) partials; 64-lane sum counts each (pixel,row) once
#pragma unroll
    for (int off = 32; off > 0; off >>= 1)
        lterm += __shfl_xor(lterm, off, 64);
    if (l == 0)
        atomicAdd(&loss_acc[(blockIdx.x & 31) * 32], lterm);   // 32-way spread
}

// ---------------------------------------------------------------------------
// k2: finalize loss (sum the 32 slots)
// ---------------------------------------------------------------------------
__global__ void k2_fin(const float* __restrict__ loss_acc,
                       float* __restrict__ out) {
    float s = 0.f;
#pragma unroll
    for (int i = 0; i < 32; ++i) s += loss_acc[i * 32];
    out[0] = -s * (1.0f / (float)NPIX);
}

extern "C" void kernel_launch(void* const* d_in, const int* in_sizes, int n_in,
                              void* d_out, int out_size, void* d_ws, size_t ws_size,
                              hipStream_t stream) {
    const float* x     = (const float*)d_in[0];
    const float* cl    = (const float*)d_in[1];
    const float* alpha = (const float*)d_in[2];
    float* out = (float*)d_out;

    float*          loss_acc = (float*)d_ws;                       // 32 slots x 128B
    unsigned short* clAhi    = (unsigned short*)((char*)d_ws + 4096);
    unsigned short* clAlo    = clAhi + 32 * 64 * 8;                // +32KB

    hipLaunchKernelGGL(k0_prep, dim3(32), dim3(64), 0, stream,
                       cl, clAhi, clAlo, loss_acc);
    hipLaunchKernelGGL(k1_main, dim3(NPIX / 32), dim3(64), 0, stream,
                       x, clAhi, clAlo, alpha, out, loss_acc);
    hipLaunchKernelGGL(k2_fin, dim3(1), dim3(1), 0, stream, loss_acc, out);
}